// Round 1
// baseline (486.622 us; speedup 1.0000x reference)
//
#include <hip/hip_runtime.h>

#define N_NODES  100000
#define N_EDGES  1250000
#define F_IN     128
#define F_OUT    64
#define N_GRAPHS 256

// ---------------- degree count over targets (col) ----------------
__global__ __launch_bounds__(256) void deg_count_k(const int* __restrict__ col,
                                                   int* __restrict__ deg) {
    int t = blockIdx.x * blockDim.x + threadIdx.x;
    int stride = gridDim.x * blockDim.x;
    for (int e = t; e < N_EDGES; e += stride)
        atomicAdd(&deg[col[e]], 1);
}

// ---------------- dis = rsqrt(deg + 1)  (self-loop included) ----------------
__global__ __launch_bounds__(256) void dis_k(const int* __restrict__ deg,
                                             float* __restrict__ dis) {
    int i = blockIdx.x * blockDim.x + threadIdx.x;
    if (i < N_NODES) dis[i] = rsqrtf((float)deg[i] + 1.0f);
}

// ---------------- y = dis[i] * (node_feat @ W^T); agg init = y ----------------
// Block: 256 threads = 4 waves; each wave = 64 lanes = 64 output features.
// Each sub-group (wave) handles 4 nodes -> 16 nodes/block. N divisible by 16.
__global__ __launch_bounds__(256) void linear_k(const float* __restrict__ x,
                                                const float* __restrict__ W,
                                                const float* __restrict__ dis,
                                                float* __restrict__ y,
                                                float* __restrict__ agg) {
    __shared__ float Wt[F_IN * F_OUT];  // transposed: Wt[k*64 + f]
    int tid = threadIdx.x;
    #pragma unroll
    for (int i = 0; i < (F_IN * F_OUT) / 256; ++i) {
        int idx = i * 256 + tid;          // coalesced read of W [64][128]
        int f = idx >> 7, k = idx & 127;
        Wt[k * F_OUT + f] = W[idx];
    }
    __syncthreads();

    int f   = tid & 63;
    int sub = tid >> 6;                   // 0..3
    int base = blockIdx.x * 16 + sub * 4; // 4 consecutive nodes per wave

    const float4* x0 = (const float4*)(x + (size_t)(base + 0) * F_IN);
    const float4* x1 = (const float4*)(x + (size_t)(base + 1) * F_IN);
    const float4* x2 = (const float4*)(x + (size_t)(base + 2) * F_IN);
    const float4* x3 = (const float4*)(x + (size_t)(base + 3) * F_IN);

    float acc0 = 0.f, acc1 = 0.f, acc2 = 0.f, acc3 = 0.f;
    #pragma unroll 4
    for (int k4 = 0; k4 < F_IN / 4; ++k4) {
        float4 a = x0[k4], b = x1[k4], c = x2[k4], d = x3[k4];
        float w0 = Wt[(k4 * 4 + 0) * F_OUT + f];
        float w1 = Wt[(k4 * 4 + 1) * F_OUT + f];
        float w2 = Wt[(k4 * 4 + 2) * F_OUT + f];
        float w3 = Wt[(k4 * 4 + 3) * F_OUT + f];
        acc0 = fmaf(a.x, w0, fmaf(a.y, w1, fmaf(a.z, w2, fmaf(a.w, w3, acc0))));
        acc1 = fmaf(b.x, w0, fmaf(b.y, w1, fmaf(b.z, w2, fmaf(b.w, w3, acc1))));
        acc2 = fmaf(c.x, w0, fmaf(c.y, w1, fmaf(c.z, w2, fmaf(c.w, w3, acc2))));
        acc3 = fmaf(d.x, w0, fmaf(d.y, w1, fmaf(d.z, w2, fmaf(d.w, w3, acc3))));
    }

    float d0 = dis[base + 0], d1 = dis[base + 1];
    float d2 = dis[base + 2], d3 = dis[base + 3];
    size_t o0 = (size_t)(base + 0) * F_OUT + f;
    size_t o1 = (size_t)(base + 1) * F_OUT + f;
    size_t o2 = (size_t)(base + 2) * F_OUT + f;
    size_t o3 = (size_t)(base + 3) * F_OUT + f;
    float v0 = acc0 * d0, v1 = acc1 * d1, v2 = acc2 * d2, v3 = acc3 * d3;
    y[o0] = v0; y[o1] = v1; y[o2] = v2; y[o3] = v3;
    agg[o0] = v0; agg[o1] = v1; agg[o2] = v2; agg[o3] = v3;  // self-loop init
}

// ---------------- edge scatter: agg[col] += y[row]  ----------------
// One wave per edge; lane = feature. Coalesced 256B gather + 256B atomic add.
__global__ __launch_bounds__(256) void scatter_k(const int* __restrict__ row,
                                                 const int* __restrict__ col,
                                                 const float* __restrict__ y,
                                                 float* __restrict__ agg) {
    int lane = threadIdx.x & 63;
    int wid  = (blockIdx.x * blockDim.x + threadIdx.x) >> 6;
    int nw   = (gridDim.x * blockDim.x) >> 6;
    for (int e = wid; e < N_EDGES; e += nw) {
        int r = row[e];
        int c = col[e];
        float v = y[(size_t)r * F_OUT + lane];
        atomicAdd(&agg[(size_t)c * F_OUT + lane], v);
    }
}

// ---------------- relu(dis*agg + b) then mean-pool (batch sorted) ----------------
// Block 256 = 4 waves; each wave handles 64 consecutive nodes; run-length
// accumulation per graph id -> one atomic per (wave, graph-run).
__global__ __launch_bounds__(256) void pool_k(const float* __restrict__ agg,
                                              const float* __restrict__ dis,
                                              const int* __restrict__ batch,
                                              const float* __restrict__ bias,
                                              float* __restrict__ psum,
                                              int* __restrict__ pcnt) {
    int lane = threadIdx.x & 63;
    int wid  = threadIdx.x >> 6;
    int base = blockIdx.x * 256 + wid * 64;
    float bf = bias[lane];

    float racc = 0.f;
    int cur = -1, runlen = 0;
    for (int n = 0; n < 64; ++n) {
        int i = base + n;
        if (i >= N_NODES) break;
        int g = batch[i];
        float v = fmaxf(fmaf(dis[i], agg[(size_t)i * F_OUT + lane], bf), 0.f);
        if (g != cur) {
            if (cur >= 0) {
                atomicAdd(&psum[cur * F_OUT + lane], racc);
                if (lane == 0) atomicAdd(&pcnt[cur], runlen);
            }
            cur = g; racc = 0.f; runlen = 0;
        }
        racc += v; runlen++;
    }
    if (cur >= 0) {
        atomicAdd(&psum[cur * F_OUT + lane], racc);
        if (lane == 0) atomicAdd(&pcnt[cur], runlen);
    }
}

// ---------------- out = psum / max(count,1) ----------------
__global__ __launch_bounds__(256) void final_k(const float* __restrict__ psum,
                                               const int* __restrict__ pcnt,
                                               float* __restrict__ out) {
    int t = blockIdx.x * blockDim.x + threadIdx.x;
    if (t < N_GRAPHS * F_OUT) {
        int g = t >> 6;
        float c = (float)(pcnt[g] > 1 ? pcnt[g] : 1);
        out[t] = psum[t] / c;
    }
}

extern "C" void kernel_launch(void* const* d_in, const int* in_sizes, int n_in,
                              void* d_out, int out_size, void* d_ws, size_t ws_size,
                              hipStream_t stream) {
    const float* node_feat = (const float*)d_in[0];
    const int*   edges     = (const int*)d_in[1];   // [2, E] flat: row then col
    const int*   batch     = (const int*)d_in[2];
    const float* W         = (const float*)d_in[3];
    const float* b         = (const float*)d_in[4];

    // workspace carve-up (~52.2 MB)
    float* y    = (float*)d_ws;                         // N*64
    float* agg  = y + (size_t)N_NODES * F_OUT;          // N*64
    float* dis  = agg + (size_t)N_NODES * F_OUT;        // N
    int*   deg  = (int*)(dis + N_NODES);                // N
    float* psum = (float*)(deg + N_NODES);              // G*64
    int*   pcnt = (int*)(psum + N_GRAPHS * F_OUT);      // G

    // zero deg + psum + pcnt (contiguous region)
    size_t zbytes = (size_t)N_NODES * 4 + (size_t)N_GRAPHS * F_OUT * 4 + (size_t)N_GRAPHS * 4;
    hipMemsetAsync(deg, 0, zbytes, stream);

    const int* row = edges;
    const int* col = edges + N_EDGES;

    deg_count_k<<<2048, 256, 0, stream>>>(col, deg);
    dis_k<<<(N_NODES + 255) / 256, 256, 0, stream>>>(deg, dis);
    linear_k<<<N_NODES / 16, 256, 0, stream>>>(node_feat, W, dis, y, agg);
    scatter_k<<<4096, 256, 0, stream>>>(row, col, y, agg);
    pool_k<<<(N_NODES + 255) / 256, 256, 0, stream>>>(agg, dis, batch, b, psum, pcnt);
    final_k<<<(N_GRAPHS * F_OUT + 255) / 256, 256, 0, stream>>>(psum, pcnt, (float*)d_out);
}

// Round 2
// 363.456 us; speedup vs baseline: 1.3389x; 1.3389x over previous
//
#include <hip/hip_runtime.h>

#define N_NODES  100000
#define N_EDGES  1250000
#define F_IN     128
#define F_OUT    64
#define N_GRAPHS 256
#define SCAN_BLK 1024
#define N_SBLK   ((N_NODES + SCAN_BLK - 1) / SCAN_BLK)   // 98

// ---------------- degree count over targets (col) ----------------
__global__ __launch_bounds__(256) void deg_count_k(const int* __restrict__ col,
                                                   int* __restrict__ deg) {
    int t = blockIdx.x * blockDim.x + threadIdx.x;
    int stride = gridDim.x * blockDim.x;
    for (int e = t; e < N_EDGES; e += stride)
        atomicAdd(&deg[col[e]], 1);
}

// ---------------- dis = rsqrt(deg + 1)  (self-loop included) ----------------
__global__ __launch_bounds__(256) void dis_k(const int* __restrict__ deg,
                                             float* __restrict__ dis) {
    int i = blockIdx.x * blockDim.x + threadIdx.x;
    if (i < N_NODES) dis[i] = rsqrtf((float)deg[i] + 1.0f);
}

// ---------------- y = dis[i] * (node_feat @ W^T) ----------------
__global__ __launch_bounds__(256) void linear_k(const float* __restrict__ x,
                                                const float* __restrict__ W,
                                                const float* __restrict__ dis,
                                                float* __restrict__ y) {
    __shared__ float Wt[F_IN * F_OUT];  // transposed: Wt[k*64 + f]
    int tid = threadIdx.x;
    #pragma unroll
    for (int i = 0; i < (F_IN * F_OUT) / 256; ++i) {
        int idx = i * 256 + tid;          // coalesced read of W [64][128]
        int f = idx >> 7, k = idx & 127;
        Wt[k * F_OUT + f] = W[idx];
    }
    __syncthreads();

    int f   = tid & 63;
    int sub = tid >> 6;                   // 0..3
    int base = blockIdx.x * 16 + sub * 4; // 4 consecutive nodes per wave

    const float4* x0 = (const float4*)(x + (size_t)(base + 0) * F_IN);
    const float4* x1 = (const float4*)(x + (size_t)(base + 1) * F_IN);
    const float4* x2 = (const float4*)(x + (size_t)(base + 2) * F_IN);
    const float4* x3 = (const float4*)(x + (size_t)(base + 3) * F_IN);

    float acc0 = 0.f, acc1 = 0.f, acc2 = 0.f, acc3 = 0.f;
    #pragma unroll 4
    for (int k4 = 0; k4 < F_IN / 4; ++k4) {
        float4 a = x0[k4], b = x1[k4], c = x2[k4], d = x3[k4];
        float w0 = Wt[(k4 * 4 + 0) * F_OUT + f];
        float w1 = Wt[(k4 * 4 + 1) * F_OUT + f];
        float w2 = Wt[(k4 * 4 + 2) * F_OUT + f];
        float w3 = Wt[(k4 * 4 + 3) * F_OUT + f];
        acc0 = fmaf(a.x, w0, fmaf(a.y, w1, fmaf(a.z, w2, fmaf(a.w, w3, acc0))));
        acc1 = fmaf(b.x, w0, fmaf(b.y, w1, fmaf(b.z, w2, fmaf(b.w, w3, acc1))));
        acc2 = fmaf(c.x, w0, fmaf(c.y, w1, fmaf(c.z, w2, fmaf(c.w, w3, acc2))));
        acc3 = fmaf(d.x, w0, fmaf(d.y, w1, fmaf(d.z, w2, fmaf(d.w, w3, acc3))));
    }

    float d0 = dis[base + 0], d1 = dis[base + 1];
    float d2 = dis[base + 2], d3 = dis[base + 3];
    y[(size_t)(base + 0) * F_OUT + f] = acc0 * d0;
    y[(size_t)(base + 1) * F_OUT + f] = acc1 * d1;
    y[(size_t)(base + 2) * F_OUT + f] = acc2 * d2;
    y[(size_t)(base + 3) * F_OUT + f] = acc3 * d3;
}

// ---------------- exclusive scan of deg -> offs (3 kernels) ----------------
__global__ __launch_bounds__(SCAN_BLK) void scan1_k(const int* __restrict__ deg,
                                                    int* __restrict__ offs,
                                                    int* __restrict__ bsum) {
    __shared__ int lds[SCAN_BLK];
    int tid = threadIdx.x;
    int i = blockIdx.x * SCAN_BLK + tid;
    int v = (i < N_NODES) ? deg[i] : 0;
    lds[tid] = v;
    __syncthreads();
    for (int off = 1; off < SCAN_BLK; off <<= 1) {
        int t = (tid >= off) ? lds[tid - off] : 0;
        __syncthreads();
        lds[tid] += t;
        __syncthreads();
    }
    if (i < N_NODES) offs[i] = lds[tid] - v;      // exclusive within block
    if (tid == SCAN_BLK - 1) bsum[blockIdx.x] = lds[tid];
}

__global__ __launch_bounds__(128) void scan2_k(int* __restrict__ bsum) {
    __shared__ int lds[128];
    int tid = threadIdx.x;
    int v = (tid < N_SBLK) ? bsum[tid] : 0;
    lds[tid] = v;
    __syncthreads();
    for (int off = 1; off < 128; off <<= 1) {
        int t = (tid >= off) ? lds[tid - off] : 0;
        __syncthreads();
        lds[tid] += t;
        __syncthreads();
    }
    if (tid < N_SBLK) bsum[tid] = lds[tid] - v;   // exclusive block offsets
}

__global__ __launch_bounds__(SCAN_BLK) void scan3_k(int* __restrict__ offs,
                                                    const int* __restrict__ bsum,
                                                    int* __restrict__ cursor) {
    int i = blockIdx.x * SCAN_BLK + threadIdx.x;
    if (i < N_NODES) {
        int o = offs[i] + bsum[blockIdx.x];
        offs[i] = o;
        cursor[i] = o;
    }
}

// ---------------- fill CSR bucket: bucket[slot] = row ----------------
__global__ __launch_bounds__(256) void fill_k(const int* __restrict__ row,
                                              const int* __restrict__ col,
                                              int* __restrict__ cursor,
                                              int* __restrict__ bucket) {
    int t = blockIdx.x * blockDim.x + threadIdx.x;
    int stride = gridDim.x * blockDim.x;
    for (int e = t; e < N_EDGES; e += stride) {
        int c = col[e];
        int r = row[e];
        int p = atomicAdd(&cursor[c], 1);
        bucket[p] = r;
    }
}

// ---------------- fused gather + epilogue + mean-pool ----------------
// 4 waves/block, each wave handles 8 consecutive nodes; lane = feature.
// After fill_k, cursor[i] == offs[i] + deg[i] (bucket end).
__global__ __launch_bounds__(256) void gather_pool_k(const float* __restrict__ y,
                                                     const int* __restrict__ offs,
                                                     const int* __restrict__ cend,
                                                     const int* __restrict__ bucket,
                                                     const float* __restrict__ dis,
                                                     const int* __restrict__ batch,
                                                     const float* __restrict__ bias,
                                                     float* __restrict__ psum,
                                                     int* __restrict__ pcnt) {
    int lane = threadIdx.x & 63;
    int wid  = threadIdx.x >> 6;
    int i0   = (blockIdx.x * 4 + wid) * 8;   // 100000 = 3125 * 32, exact
    float bf = bias[lane];

    float racc = 0.f;
    int cur = -1, runlen = 0;
    for (int n = 0; n < 8; ++n) {
        int i = i0 + n;
        int s = __builtin_amdgcn_readfirstlane(offs[i]);
        int e = __builtin_amdgcn_readfirstlane(cend[i]);
        float acc = y[(size_t)i * F_OUT + lane];   // self-loop: dis[i]*y[i] term
        int j = s;
        for (; j + 3 < e; j += 4) {
            int r0 = bucket[j], r1 = bucket[j + 1];
            int r2 = bucket[j + 2], r3 = bucket[j + 3];
            float v0 = y[(size_t)r0 * F_OUT + lane];
            float v1 = y[(size_t)r1 * F_OUT + lane];
            float v2 = y[(size_t)r2 * F_OUT + lane];
            float v3 = y[(size_t)r3 * F_OUT + lane];
            acc += (v0 + v1) + (v2 + v3);
        }
        for (; j < e; ++j)
            acc += y[(size_t)bucket[j] * F_OUT + lane];

        float v = fmaxf(fmaf(dis[i], acc, bf), 0.f);
        int g = batch[i];
        if (g != cur) {
            if (cur >= 0) {
                atomicAdd(&psum[cur * F_OUT + lane], racc);
                if (lane == 0) atomicAdd(&pcnt[cur], runlen);
            }
            cur = g; racc = 0.f; runlen = 0;
        }
        racc += v; runlen++;
    }
    if (cur >= 0) {
        atomicAdd(&psum[cur * F_OUT + lane], racc);
        if (lane == 0) atomicAdd(&pcnt[cur], runlen);
    }
}

// ---------------- out = psum / max(count,1) ----------------
__global__ __launch_bounds__(256) void final_k(const float* __restrict__ psum,
                                               const int* __restrict__ pcnt,
                                               float* __restrict__ out) {
    int t = blockIdx.x * blockDim.x + threadIdx.x;
    if (t < N_GRAPHS * F_OUT) {
        int g = t >> 6;
        float c = (float)(pcnt[g] > 1 ? pcnt[g] : 1);
        out[t] = psum[t] / c;
    }
}

extern "C" void kernel_launch(void* const* d_in, const int* in_sizes, int n_in,
                              void* d_out, int out_size, void* d_ws, size_t ws_size,
                              hipStream_t stream) {
    const float* node_feat = (const float*)d_in[0];
    const int*   edges     = (const int*)d_in[1];   // [2, E] flat: row then col
    const int*   batch     = (const int*)d_in[2];
    const float* W         = (const float*)d_in[3];
    const float* b         = (const float*)d_in[4];

    // workspace carve-up (~32 MB)
    float* y      = (float*)d_ws;                        // N*64
    int*   deg    = (int*)(y + (size_t)N_NODES * F_OUT); // N
    float* psum   = (float*)(deg + N_NODES);             // G*64
    int*   pcnt   = (int*)(psum + N_GRAPHS * F_OUT);     // G
    float* dis    = (float*)(pcnt + N_GRAPHS);           // N
    int*   offs   = (int*)(dis + N_NODES);               // N
    int*   cursor = offs + N_NODES;                      // N
    int*   bsum   = cursor + N_NODES;                    // 128
    int*   bucket = bsum + 128;                          // E

    // zero deg + psum + pcnt (contiguous)
    size_t zbytes = ((size_t)N_NODES + N_GRAPHS * F_OUT + N_GRAPHS) * 4;
    hipMemsetAsync(deg, 0, zbytes, stream);

    const int* row = edges;
    const int* col = edges + N_EDGES;

    deg_count_k<<<2048, 256, 0, stream>>>(col, deg);
    dis_k<<<(N_NODES + 255) / 256, 256, 0, stream>>>(deg, dis);
    linear_k<<<N_NODES / 16, 256, 0, stream>>>(node_feat, W, dis, y);
    scan1_k<<<N_SBLK, SCAN_BLK, 0, stream>>>(deg, offs, bsum);
    scan2_k<<<1, 128, 0, stream>>>(bsum);
    scan3_k<<<N_SBLK, SCAN_BLK, 0, stream>>>(offs, bsum, cursor);
    fill_k<<<2048, 256, 0, stream>>>(row, col, cursor, bucket);
    gather_pool_k<<<N_NODES / 32, 256, 0, stream>>>(y, offs, cursor, bucket,
                                                    dis, batch, b, psum, pcnt);
    final_k<<<(N_GRAPHS * F_OUT + 255) / 256, 256, 0, stream>>>(psum, pcnt, (float*)d_out);
}

// Round 3
// 334.851 us; speedup vs baseline: 1.4532x; 1.0854x over previous
//
#include <hip/hip_runtime.h>

#define N_NODES  100000
#define N_EDGES  1250000
#define F_IN     128
#define F_OUT    64
#define N_GRAPHS 256
#define SCAN_BLK 1024
#define N_SBLK   ((N_NODES + SCAN_BLK - 1) / SCAN_BLK)   // 98
#define WT_LD    65   // padded leading dim: breaks the ds_write 64->1 bank conflict

// ---------------- degree count over targets (col) ----------------
__global__ __launch_bounds__(256) void deg_count_k(const int* __restrict__ col,
                                                   int* __restrict__ deg) {
    int t = blockIdx.x * blockDim.x + threadIdx.x;
    int stride = gridDim.x * blockDim.x;
    for (int e = t; e < N_EDGES; e += stride)
        atomicAdd(&deg[col[e]], 1);
}

// ---------------- dis = rsqrt(deg + 1)  (self-loop included) ----------------
__global__ __launch_bounds__(256) void dis_k(const int* __restrict__ deg,
                                             float* __restrict__ dis) {
    int i = blockIdx.x * blockDim.x + threadIdx.x;
    if (i < N_NODES) dis[i] = rsqrtf((float)deg[i] + 1.0f);
}

// ---------------- y = dis[i] * (node_feat @ W^T) ----------------
// 4 waves/block; wave = 64 lanes = 64 output features; 8 nodes per wave.
__global__ __launch_bounds__(256) void linear_k(const float* __restrict__ x,
                                                const float* __restrict__ W,
                                                const float* __restrict__ dis,
                                                float* __restrict__ y) {
    __shared__ float Wt[F_IN * WT_LD];   // Wt[k*65 + f]
    int tid = threadIdx.x;
    #pragma unroll
    for (int i = 0; i < (F_IN * F_OUT) / 256; ++i) {
        int idx = i * 256 + tid;          // coalesced read of W [64][128]
        int f = idx >> 7, k = idx & 127;
        Wt[k * WT_LD + f] = W[idx];       // bank (k+f)%32: 2-way, free
    }
    __syncthreads();

    int f    = tid & 63;
    int sub  = tid >> 6;                  // 0..3
    int base = blockIdx.x * 32 + sub * 8; // 8 consecutive nodes per wave
    const float* xp = x + (size_t)base * F_IN;

    float acc[8];
    #pragma unroll
    for (int n = 0; n < 8; ++n) acc[n] = 0.f;

    #pragma unroll 4
    for (int k4 = 0; k4 < F_IN / 4; ++k4) {
        float w0 = Wt[(k4 * 4 + 0) * WT_LD + f];
        float w1 = Wt[(k4 * 4 + 1) * WT_LD + f];
        float w2 = Wt[(k4 * 4 + 2) * WT_LD + f];
        float w3 = Wt[(k4 * 4 + 3) * WT_LD + f];
        #pragma unroll
        for (int n = 0; n < 8; ++n) {
            float4 a = *(const float4*)(xp + (size_t)n * F_IN + k4 * 4);
            acc[n] = fmaf(a.x, w0, fmaf(a.y, w1, fmaf(a.z, w2, fmaf(a.w, w3, acc[n]))));
        }
    }

    #pragma unroll
    for (int n = 0; n < 8; ++n) {
        y[(size_t)(base + n) * F_OUT + f] = acc[n] * dis[base + n];
    }
}

// ---------------- exclusive scan of deg -> offs (3 kernels) ----------------
__global__ __launch_bounds__(SCAN_BLK) void scan1_k(const int* __restrict__ deg,
                                                    int* __restrict__ offs,
                                                    int* __restrict__ bsum) {
    __shared__ int lds[SCAN_BLK];
    int tid = threadIdx.x;
    int i = blockIdx.x * SCAN_BLK + tid;
    int v = (i < N_NODES) ? deg[i] : 0;
    lds[tid] = v;
    __syncthreads();
    for (int off = 1; off < SCAN_BLK; off <<= 1) {
        int t = (tid >= off) ? lds[tid - off] : 0;
        __syncthreads();
        lds[tid] += t;
        __syncthreads();
    }
    if (i < N_NODES) offs[i] = lds[tid] - v;      // exclusive within block
    if (tid == SCAN_BLK - 1) bsum[blockIdx.x] = lds[tid];
}

__global__ __launch_bounds__(128) void scan2_k(int* __restrict__ bsum) {
    __shared__ int lds[128];
    int tid = threadIdx.x;
    int v = (tid < N_SBLK) ? bsum[tid] : 0;
    lds[tid] = v;
    __syncthreads();
    for (int off = 1; off < 128; off <<= 1) {
        int t = (tid >= off) ? lds[tid - off] : 0;
        __syncthreads();
        lds[tid] += t;
        __syncthreads();
    }
    if (tid < N_SBLK) bsum[tid] = lds[tid] - v;   // exclusive block offsets
}

__global__ __launch_bounds__(SCAN_BLK) void scan3_k(int* __restrict__ offs,
                                                    const int* __restrict__ bsum,
                                                    int* __restrict__ cursor) {
    int i = blockIdx.x * SCAN_BLK + threadIdx.x;
    if (i < N_NODES) {
        int o = offs[i] + bsum[blockIdx.x];
        offs[i] = o;
        cursor[i] = o;
    }
}

// ---------------- fill CSR bucket: bucket[slot] = row ----------------
__global__ __launch_bounds__(256) void fill_k(const int* __restrict__ row,
                                              const int* __restrict__ col,
                                              int* __restrict__ cursor,
                                              int* __restrict__ bucket) {
    int t = blockIdx.x * blockDim.x + threadIdx.x;
    int stride = gridDim.x * blockDim.x;
    for (int e = t; e < N_EDGES; e += stride) {
        int c = col[e];
        int r = row[e];
        int p = atomicAdd(&cursor[c], 1);
        bucket[p] = r;
    }
}

// ---------------- fused gather + epilogue + mean-pool ----------------
// 4 waves/block, each wave handles 8 consecutive nodes; lane = feature.
// After fill_k, cursor[i] == offs[i] + deg[i] (bucket end).
__global__ __launch_bounds__(256) void gather_pool_k(const float* __restrict__ y,
                                                     const int* __restrict__ offs,
                                                     const int* __restrict__ cend,
                                                     const int* __restrict__ bucket,
                                                     const float* __restrict__ dis,
                                                     const int* __restrict__ batch,
                                                     const float* __restrict__ bias,
                                                     float* __restrict__ psum,
                                                     int* __restrict__ pcnt) {
    int lane = threadIdx.x & 63;
    int wid  = threadIdx.x >> 6;
    int i0   = (blockIdx.x * 4 + wid) * 8;   // 100000 = 3125 * 32, exact
    float bf = bias[lane];

    float racc = 0.f;
    int cur = -1, runlen = 0;
    for (int n = 0; n < 8; ++n) {
        int i = i0 + n;
        int s = __builtin_amdgcn_readfirstlane(offs[i]);
        int e = __builtin_amdgcn_readfirstlane(cend[i]);
        float acc = y[(size_t)i * F_OUT + lane];   // self-loop: dis[i]*y[i] term
        int j = s;
        for (; j + 3 < e; j += 4) {
            int r0 = bucket[j], r1 = bucket[j + 1];
            int r2 = bucket[j + 2], r3 = bucket[j + 3];
            float v0 = y[(size_t)r0 * F_OUT + lane];
            float v1 = y[(size_t)r1 * F_OUT + lane];
            float v2 = y[(size_t)r2 * F_OUT + lane];
            float v3 = y[(size_t)r3 * F_OUT + lane];
            acc += (v0 + v1) + (v2 + v3);
        }
        for (; j < e; ++j)
            acc += y[(size_t)bucket[j] * F_OUT + lane];

        float v = fmaxf(fmaf(dis[i], acc, bf), 0.f);
        int g = batch[i];
        if (g != cur) {
            if (cur >= 0) {
                atomicAdd(&psum[cur * F_OUT + lane], racc);
                if (lane == 0) atomicAdd(&pcnt[cur], runlen);
            }
            cur = g; racc = 0.f; runlen = 0;
        }
        racc += v; runlen++;
    }
    if (cur >= 0) {
        atomicAdd(&psum[cur * F_OUT + lane], racc);
        if (lane == 0) atomicAdd(&pcnt[cur], runlen);
    }
}

// ---------------- out = psum / max(count,1) ----------------
__global__ __launch_bounds__(256) void final_k(const float* __restrict__ psum,
                                               const int* __restrict__ pcnt,
                                               float* __restrict__ out) {
    int t = blockIdx.x * blockDim.x + threadIdx.x;
    if (t < N_GRAPHS * F_OUT) {
        int g = t >> 6;
        float c = (float)(pcnt[g] > 1 ? pcnt[g] : 1);
        out[t] = psum[t] / c;
    }
}

extern "C" void kernel_launch(void* const* d_in, const int* in_sizes, int n_in,
                              void* d_out, int out_size, void* d_ws, size_t ws_size,
                              hipStream_t stream) {
    const float* node_feat = (const float*)d_in[0];
    const int*   edges     = (const int*)d_in[1];   // [2, E] flat: row then col
    const int*   batch     = (const int*)d_in[2];
    const float* W         = (const float*)d_in[3];
    const float* b         = (const float*)d_in[4];

    // workspace carve-up (~32 MB)
    float* y      = (float*)d_ws;                        // N*64
    int*   deg    = (int*)(y + (size_t)N_NODES * F_OUT); // N
    float* psum   = (float*)(deg + N_NODES);             // G*64
    int*   pcnt   = (int*)(psum + N_GRAPHS * F_OUT);     // G
    float* dis    = (float*)(pcnt + N_GRAPHS);           // N
    int*   offs   = (int*)(dis + N_NODES);               // N
    int*   cursor = offs + N_NODES;                      // N
    int*   bsum   = cursor + N_NODES;                    // 128
    int*   bucket = bsum + 128;                          // E

    // zero deg + psum + pcnt (contiguous)
    size_t zbytes = ((size_t)N_NODES + N_GRAPHS * F_OUT + N_GRAPHS) * 4;
    hipMemsetAsync(deg, 0, zbytes, stream);

    const int* row = edges;
    const int* col = edges + N_EDGES;

    deg_count_k<<<2048, 256, 0, stream>>>(col, deg);
    dis_k<<<(N_NODES + 255) / 256, 256, 0, stream>>>(deg, dis);
    linear_k<<<N_NODES / 32, 256, 0, stream>>>(node_feat, W, dis, y);
    scan1_k<<<N_SBLK, SCAN_BLK, 0, stream>>>(deg, offs, bsum);
    scan2_k<<<1, 128, 0, stream>>>(bsum);
    scan3_k<<<N_SBLK, SCAN_BLK, 0, stream>>>(offs, bsum, cursor);
    fill_k<<<2048, 256, 0, stream>>>(row, col, cursor, bucket);
    gather_pool_k<<<N_NODES / 32, 256, 0, stream>>>(y, offs, cursor, bucket,
                                                    dis, batch, b, psum, pcnt);
    final_k<<<(N_GRAPHS * F_OUT + 255) / 256, 256, 0, stream>>>(psum, pcnt, (float*)d_out);
}